// Round 2
// baseline (696.988 us; speedup 1.0000x reference)
//
#include <hip/hip_runtime.h>
#include <math.h>

#define BB 32
#define LL 8192
#define DD 512
#define CHUNKS 64                       // blocks per batch in pass 1
#define ROWS_PER_BLOCK (LL / CHUNKS)    // 128 rows/block, 32 rows/wave
#define NCHUNK CHUNKS                   // partials per batch (1 per block)
#define PSTRIDE (2 + DD)                // [m, s, ctx[512]]

// ws float layout
#define TV_OFF ((size_t)BB * NCHUNK * PSTRIDE)   // partials: 32*64*514 floats
#define MS_OFF (TV_OFF + (size_t)BB * 1024)      // tanh vectors: B*1024
// ms: B*2 floats (m_b, 1/s_b). Total ws use ~4.4 MB.

__device__ __forceinline__ float dot8(const float4& x0, const float4& x1,
                                      const float4& y0, const float4& y1) {
    return x0.x*y0.x + x0.y*y0.y + x0.z*y0.z + x0.w*y0.w
         + x1.x*y1.x + x1.y*y1.y + x1.z*y1.z + x1.w*y1.w;
}

// ---------------- Pass 1: scores + online-softmax partial context ----------------
__global__ __launch_bounds__(256) void la_pass1(const float* __restrict__ h,
                                                const float* __restrict__ s,
                                                float* __restrict__ eOut,
                                                float* __restrict__ ws) {
    const int b     = blockIdx.x / CHUNKS;
    const int chunk = blockIdx.x % CHUNKS;
    const int tid   = threadIdx.x;
    const int wave  = tid >> 6;
    const int lane  = tid & 63;

    const float4* s4 = (const float4*)(s + (size_t)b * DD);
    const float4 sv0 = s4[lane];
    const float4 sv1 = s4[lane + 64];

    // dual independent online-softmax states (A: even row, B: odd row)
    float mA = -INFINITY, sA = 0.0f;
    float4 a0 = {0.f,0.f,0.f,0.f}, a1 = {0.f,0.f,0.f,0.f};
    float mB = -INFINITY, sB = 0.0f;
    float4 b0 = {0.f,0.f,0.f,0.f}, b1 = {0.f,0.f,0.f,0.f};

    __shared__ float esc[ROWS_PER_BLOCK];
    __shared__ float lm[4], lsum[4];
    __shared__ float lctx[4][DD];

    const int l0 = chunk * ROWS_PER_BLOCK;
    const float4* hbase = (const float4*)(h + ((size_t)b * LL + l0) * DD);

    for (int i = 0; i < ROWS_PER_BLOCK / 8; ++i) {
        const int r0 = i * 8 + wave * 2;          // this wave's even row
        const float4* row0 = hbase + (size_t)r0 * (DD / 4);
        const float4* row1 = row0 + (DD / 4);
        float4 h00 = row0[lane];
        float4 h01 = row0[lane + 64];
        float4 h10 = row1[lane];
        float4 h11 = row1[lane + 64];
        float d0 = dot8(h00, h01, sv0, sv1);
        float d1 = dot8(h10, h11, sv0, sv1);
        #pragma unroll
        for (int off = 32; off > 0; off >>= 1) {   // interleaved butterflies
            d0 += __shfl_xor(d0, off, 64);
            d1 += __shfl_xor(d1, off, 64);
        }
        if (lane == 0) { esc[r0] = d0; esc[r0 + 1] = d1; }

        // deferred-rescale online update; dot is wave-uniform -> uniform branch
        if (d0 <= mA) {
            float p = __expf(d0 - mA);
            sA += p;
            a0.x += p*h00.x; a0.y += p*h00.y; a0.z += p*h00.z; a0.w += p*h00.w;
            a1.x += p*h01.x; a1.y += p*h01.y; a1.z += p*h01.z; a1.w += p*h01.w;
        } else {
            float c = __expf(mA - d0);             // 0 on first iter (mA=-inf)
            sA = sA*c + 1.0f;
            a0.x = a0.x*c + h00.x; a0.y = a0.y*c + h00.y;
            a0.z = a0.z*c + h00.z; a0.w = a0.w*c + h00.w;
            a1.x = a1.x*c + h01.x; a1.y = a1.y*c + h01.y;
            a1.z = a1.z*c + h01.z; a1.w = a1.w*c + h01.w;
            mA = d0;
        }
        if (d1 <= mB) {
            float p = __expf(d1 - mB);
            sB += p;
            b0.x += p*h10.x; b0.y += p*h10.y; b0.z += p*h10.z; b0.w += p*h10.w;
            b1.x += p*h11.x; b1.y += p*h11.y; b1.z += p*h11.z; b1.w += p*h11.w;
        } else {
            float c = __expf(mB - d1);
            sB = sB*c + 1.0f;
            b0.x = b0.x*c + h10.x; b0.y = b0.y*c + h10.y;
            b0.z = b0.z*c + h10.z; b0.w = b0.w*c + h10.w;
            b1.x = b1.x*c + h11.x; b1.y = b1.y*c + h11.y;
            b1.z = b1.z*c + h11.z; b1.w = b1.w*c + h11.w;
            mB = d1;
        }
    }

    // merge dual states in-register
    const float mw = fmaxf(mA, mB);
    const float wa = __expf(mA - mw), wb = __expf(mB - mw);
    const float sw = sA*wa + sB*wb;
    a0.x = a0.x*wa + b0.x*wb; a0.y = a0.y*wa + b0.y*wb;
    a0.z = a0.z*wa + b0.z*wb; a0.w = a0.w*wa + b0.w*wb;
    a1.x = a1.x*wa + b1.x*wb; a1.y = a1.y*wa + b1.y*wb;
    a1.z = a1.z*wa + b1.z*wb; a1.w = a1.w*wa + b1.w*wb;

    // cross-wave combine in LDS
    lctx[wave][4*lane + 0] = a0.x;  lctx[wave][4*lane + 1] = a0.y;
    lctx[wave][4*lane + 2] = a0.z;  lctx[wave][4*lane + 3] = a0.w;
    lctx[wave][256 + 4*lane + 0] = a1.x;  lctx[wave][256 + 4*lane + 1] = a1.y;
    lctx[wave][256 + 4*lane + 2] = a1.z;  lctx[wave][256 + 4*lane + 3] = a1.w;
    if (lane == 0) { lm[wave] = mw; lsum[wave] = sw; }
    __syncthreads();

    const float mb_ = fmaxf(fmaxf(lm[0], lm[1]), fmaxf(lm[2], lm[3]));
    const float w0 = __expf(lm[0] - mb_), w1 = __expf(lm[1] - mb_);
    const float w2 = __expf(lm[2] - mb_), w3 = __expf(lm[3] - mb_);
    const float sb_ = lsum[0]*w0 + lsum[1]*w1 + lsum[2]*w2 + lsum[3]*w3;

    float* p = ws + ((size_t)b * NCHUNK + chunk) * PSTRIDE;
    if (tid == 0) { p[0] = mb_; p[1] = sb_; }
    p[2 + tid]       = lctx[0][tid]*w0     + lctx[1][tid]*w1     + lctx[2][tid]*w2     + lctx[3][tid]*w3;
    p[2 + 256 + tid] = lctx[0][256+tid]*w0 + lctx[1][256+tid]*w1 + lctx[2][256+tid]*w2 + lctx[3][256+tid]*w3;

    // coalesced raw-score write
    if (tid < ROWS_PER_BLOCK) eOut[(size_t)b * LL + l0 + tid] = esc[tid];
}

// ---------------- Pass 2: combine partials -> tanh vector + (m, 1/s) ----------------
__global__ __launch_bounds__(256) void la_pass2(const float* __restrict__ s,
                                                float* __restrict__ ws) {
    const int b = blockIdx.x;
    const int t = threadIdx.x;
    __shared__ float cm[NCHUNK], cs[NCHUNK], cw[NCHUNK];
    const float* pb = ws + (size_t)b * NCHUNK * PSTRIDE;
    if (t < NCHUNK) {
        cm[t] = pb[(size_t)t * PSTRIDE];
        cs[t] = pb[(size_t)t * PSTRIDE + 1];
    }
    __syncthreads();
    float mb = -INFINITY;
    for (int c = 0; c < NCHUNK; ++c) mb = fmaxf(mb, cm[c]);
    float sb = 0.0f;
    for (int c = 0; c < NCHUNK; ++c) sb += cs[c] * __expf(cm[c] - mb);
    if (t < NCHUNK) cw[t] = __expf(cm[t] - mb);
    __syncthreads();
    const float rcp = 1.0f / sb;

    float acc0 = 0.0f, acc1 = 0.0f;
    for (int c = 0; c < NCHUNK; ++c) {
        const float* pc = pb + (size_t)c * PSTRIDE + 2;
        acc0 += cw[c] * pc[t];
        acc1 += cw[c] * pc[t + 256];
    }
    float* tv = ws + TV_OFF + (size_t)b * 1024;
    tv[t]             = tanhf(acc0 * rcp);
    tv[t + 256]       = tanhf(acc1 * rcp);
    tv[512 + t]       = tanhf(s[(size_t)b * DD + t]);
    tv[512 + t + 256] = tanhf(s[(size_t)b * DD + t + 256]);
    if (t == 0) { ws[MS_OFF + 2*b] = mb; ws[MS_OFF + 2*b + 1] = rcp; }
}

// ---------------- Pass 3: normalize scores in-place (a = exp(e-m)/s) ----------------
__global__ __launch_bounds__(256) void la_pass3(float* __restrict__ out,
                                                const float* __restrict__ ws) {
    const int i4 = blockIdx.x * 256 + threadIdx.x;   // B*L/4 = 65536 float4s
    const int b  = i4 >> 11;                         // L/4 = 2048 per batch
    const float mb  = ws[MS_OFF + 2*b];
    const float rcp = ws[MS_OFF + 2*b + 1];
    float4* o4 = (float4*)out;
    float4 e = o4[i4];
    e.x = __expf(e.x - mb) * rcp;
    e.y = __expf(e.y - mb) * rcp;
    e.z = __expf(e.z - mb) * rcp;
    e.w = __expf(e.w - mb) * rcp;
    o4[i4] = e;
}

// ---------------- Pass 4: projection att = tanhvec @ W^T + b (one wave/output) ----------------
__global__ __launch_bounds__(256) void la_pass4(const float* __restrict__ W,
                                                const float* __restrict__ bias,
                                                const float* __restrict__ ws,
                                                float* __restrict__ attOut) {
    const int wv   = blockIdx.x * 4 + (threadIdx.x >> 6);  // global wave id = output id
    const int lane = threadIdx.x & 63;
    const int b = wv >> 9;          // / 512
    const int o = wv & 511;
    const float4* w4 = (const float4*)(W + (size_t)o * 1024);
    const float4* t4 = (const float4*)(ws + TV_OFF + (size_t)b * 1024);
    float acc = 0.0f;
    #pragma unroll
    for (int j = 0; j < 4; ++j) {
        float4 wl = w4[lane + 64*j];
        float4 tl = t4[lane + 64*j];
        acc += wl.x*tl.x + wl.y*tl.y + wl.z*tl.z + wl.w*tl.w;
    }
    #pragma unroll
    for (int off = 32; off > 0; off >>= 1) acc += __shfl_xor(acc, off, 64);
    if (lane == 0) attOut[(size_t)b * DD + o] = acc + bias[o];
}

extern "C" void kernel_launch(void* const* d_in, const int* in_sizes, int n_in,
                              void* d_out, int out_size, void* d_ws, size_t ws_size,
                              hipStream_t stream) {
    const float* h_j    = (const float*)d_in[0];   // [B, L, D]
    const float* s_i    = (const float*)d_in[1];   // [B, 1, D]
    const float* W_proj = (const float*)d_in[2];   // [D, 2D]
    const float* b_proj = (const float*)d_in[3];   // [D]
    float* out = (float*)d_out;                    // [B*L] a  ++  [B*D] att
    float* ws  = (float*)d_ws;

    float* eOut   = out;                           // raw scores -> normalized in pass 3
    float* attOut = out + (size_t)BB * LL;

    la_pass1<<<BB * CHUNKS, 256, 0, stream>>>(h_j, s_i, eOut, ws);
    la_pass2<<<BB, 256, 0, stream>>>(s_i, ws);
    la_pass3<<<(BB * LL / 4) / 256, 256, 0, stream>>>(out, ws);
    la_pass4<<<(BB * DD / 4), 256, 0, stream>>>(W_proj, b_proj, ws, attOut);
}